// Round 6
// baseline (220.879 us; speedup 1.0000x reference)
//
#include <hip/hip_runtime.h>

#define NN 50000
#define NE 800000
#define NEG_SLOPE 0.2f

__device__ __forceinline__ float lrelu(float v) { return v > 0.f ? v : NEG_SLOPE * v; }
__device__ __forceinline__ float bf2f(unsigned short u) { return __uint_as_float((unsigned)u << 16); }
__device__ __forceinline__ unsigned short f2bf(float f) {
    unsigned u = __float_as_uint(f);
    return (unsigned short)((u + 0x7FFFu + ((u >> 16) & 1u)) >> 16);   // RNE
}

// ============ CSR build (dst-sorted) ============
__global__ void hist(const int* __restrict__ ei, int* __restrict__ deg) {
    int e = blockIdx.x * blockDim.x + threadIdx.x;
    if (e < NE) atomicAdd(&deg[ei[NE + e]], 1);
}

__global__ __launch_bounds__(256) void scan1(const int* __restrict__ deg,
                                             int* __restrict__ offs, int* __restrict__ bsum) {
    __shared__ int tmp[256];
    int i = blockIdx.x * 256 + threadIdx.x;
    int v = (i < NN) ? deg[i] : 0;
    tmp[threadIdx.x] = v;
    __syncthreads();
    for (int o = 1; o < 256; o <<= 1) {
        int t = (threadIdx.x >= o) ? tmp[threadIdx.x - o] : 0;
        __syncthreads();
        tmp[threadIdx.x] += t;
        __syncthreads();
    }
    if (i < NN) offs[i] = tmp[threadIdx.x] - v;
    if (threadIdx.x == 255) bsum[blockIdx.x] = tmp[255];
}

__global__ __launch_bounds__(256) void scan2(int* __restrict__ bsum) {
    __shared__ int tmp[256];
    int v = bsum[threadIdx.x];
    tmp[threadIdx.x] = v;
    __syncthreads();
    for (int o = 1; o < 256; o <<= 1) {
        int t = (threadIdx.x >= o) ? tmp[threadIdx.x - o] : 0;
        __syncthreads();
        tmp[threadIdx.x] += t;
        __syncthreads();
    }
    bsum[threadIdx.x] = tmp[threadIdx.x] - v;
}

__global__ void scan3(int* __restrict__ offs, const int* __restrict__ bsum,
                      int* __restrict__ cursor) {
    int i = blockIdx.x * blockDim.x + threadIdx.x;
    if (i < NN) { int o = offs[i] + bsum[i >> 8]; offs[i] = o; cursor[i] = o; }
}

__global__ void scatter(const int* __restrict__ ei, int* __restrict__ cursor,
                        int* __restrict__ srclist, int* __restrict__ dlist) {
    int e = blockIdx.x * blockDim.x + threadIdx.x;
    if (e < NE) {
        int d = ei[NE + e];
        int pos = atomicAdd(&cursor[d], 1);
        srclist[pos] = ei[e];
        dlist[pos]   = d;
    }
}

// ============ weight swizzle: W[k,c] -> WS[(k4*64+c)*4+j], k=4*k4+j ============
__global__ void prep(const float* __restrict__ W1, const float* __restrict__ W2,
                     float* __restrict__ W1S, float* __restrict__ W2S) {
    int tid = blockIdx.x * blockDim.x + threadIdx.x;
    if (tid < 8192) {
        int k = tid >> 6, c = tid & 63;
        W1S[((k >> 2) * 64 + c) * 4 + (k & 3)] = W1[k * 64 + c];
    } else if (tid < 12288) {
        int t = tid - 8192;
        int k = t >> 6, c = t & 63;
        W2S[((k >> 2) * 64 + c) * 4 + (k & 3)] = W2[k * 64 + c];
    }
}

// ============ gemm1: h1 = x @ W1 (bf16 out), logits a_s1 + packed (a_d, e_self) ============
__global__ __launch_bounds__(256) void gemm1(const float* __restrict__ x,
                                             const float* __restrict__ W1S,
                                             const float* __restrict__ att_s,
                                             const float* __restrict__ att_d,
                                             unsigned short* __restrict__ h1b,
                                             float* __restrict__ a_s,
                                             float2* __restrict__ nd1) {
    int lane = threadIdx.x & 63;
    int wv   = __builtin_amdgcn_readfirstlane(threadIdx.x >> 6);
    int n0   = blockIdx.x * 16 + wv * 4;
    const float* __restrict__ xr = x + (size_t)n0 * 128;            // uniform ptr -> s_load
    const float4* __restrict__ wp = (const float4*)W1S;
    float4 acc = {0.f, 0.f, 0.f, 0.f};
#pragma unroll 4
    for (int k4 = 0; k4 < 32; ++k4) {
        float4 w = wp[k4 * 64 + lane];
        const float* xk = xr + k4 * 4;
        acc.x += xk[0]   * w.x + xk[1]   * w.y + xk[2]   * w.z + xk[3]   * w.w;
        acc.y += xk[128] * w.x + xk[129] * w.y + xk[130] * w.z + xk[131] * w.w;
        acc.z += xk[256] * w.x + xk[257] * w.y + xk[258] * w.z + xk[259] * w.w;
        acc.w += xk[384] * w.x + xk[385] * w.y + xk[386] * w.z + xk[387] * w.w;
    }
    float as_l = att_s[lane], ad_l = att_d[lane];
    float av[4] = {acc.x, acc.y, acc.z, acc.w};
#pragma unroll
    for (int r = 0; r < 4; ++r) {
        float a = av[r];
        h1b[(size_t)(n0 + r) * 64 + lane] = f2bf(a);
        float ps = a * as_l, pd = a * ad_l;
        ps += __shfl_xor(ps, 1, 64); pd += __shfl_xor(pd, 1, 64);
        ps += __shfl_xor(ps, 2, 64); pd += __shfl_xor(pd, 2, 64);
        ps += __shfl_xor(ps, 4, 64); pd += __shfl_xor(pd, 4, 64);
        if ((lane & 7) == 0) {
            int h = lane >> 3;
            a_s[(n0 + r) * 8 + h] = ps;
            nd1[(n0 + r) * 8 + h] = make_float2(pd, lrelu(ps + pd));
        }
    }
}

// ============ eexp1: one thread per (edge, head): ex = exp(lrelu(as+ad) - es) ============
__global__ __launch_bounds__(256) void eexp1(const int* __restrict__ srclist,
                                             const int* __restrict__ dlist,
                                             const float* __restrict__ a_s,
                                             const float2* __restrict__ nd1,
                                             unsigned short* __restrict__ exb1) {
    int tid = blockIdx.x * 256 + threadIdx.x;           // grid exact: NE*8
    int e = tid >> 3, h = tid & 7;
    int s = srclist[e], d = dlist[e];
    float2 nd = nd1[d * 8 + h];
    exb1[tid] = f2bf(__expf(lrelu(a_s[s * 8 + h] + nd.x) - nd.y));
}

// ============ agg1: wave/node, 8 lanes/edge, b128 gathers; writes xh = elu(agg+b1) fp32 ============
__global__ __launch_bounds__(256) void agg1(const int* __restrict__ srclist,
                                            const int* __restrict__ offs,
                                            const int* __restrict__ degv,
                                            const unsigned short* __restrict__ exb1,
                                            const unsigned short* __restrict__ h1b,
                                            const float* __restrict__ b1,
                                            float* __restrict__ xh) {
    int wv   = threadIdx.x >> 6;
    int lane = threadIdx.x & 63;
    int d    = blockIdx.x * 4 + wv;
    int base = offs[d], dg = degv[d];
    int sub  = lane >> 3, hch = lane & 7;              // head == channel-group == hch
    float acc0 = 0.f, acc1 = 0.f, acc2 = 0.f, acc3 = 0.f;
    float acc4 = 0.f, acc5 = 0.f, acc6 = 0.f, acc7 = 0.f;
    float sm = 0.f;
#pragma unroll 2
    for (int k = sub; k < dg; k += 8) {
        int s = srclist[base + k];
        float ex = bf2f(exb1[(size_t)(base + k) * 8 + hch]);
        uint4 hv = *(const uint4*)&h1b[(size_t)s * 64 + hch * 8];
        acc0 += __uint_as_float(hv.x << 16)          * ex;
        acc1 += __uint_as_float(hv.x & 0xffff0000u)  * ex;
        acc2 += __uint_as_float(hv.y << 16)          * ex;
        acc3 += __uint_as_float(hv.y & 0xffff0000u)  * ex;
        acc4 += __uint_as_float(hv.z << 16)          * ex;
        acc5 += __uint_as_float(hv.z & 0xffff0000u)  * ex;
        acc6 += __uint_as_float(hv.w << 16)          * ex;
        acc7 += __uint_as_float(hv.w & 0xffff0000u)  * ex;
        sm += ex;
    }
    if (sub == 0) {                                    // self loop: weight exp(0)=1
        uint4 hv = *(const uint4*)&h1b[(size_t)d * 64 + hch * 8];
        acc0 += __uint_as_float(hv.x << 16);
        acc1 += __uint_as_float(hv.x & 0xffff0000u);
        acc2 += __uint_as_float(hv.y << 16);
        acc3 += __uint_as_float(hv.y & 0xffff0000u);
        acc4 += __uint_as_float(hv.z << 16);
        acc5 += __uint_as_float(hv.z & 0xffff0000u);
        acc6 += __uint_as_float(hv.w << 16);
        acc7 += __uint_as_float(hv.w & 0xffff0000u);
        sm += 1.f;
    }
#pragma unroll
    for (int m = 8; m < 64; m <<= 1) {
        acc0 += __shfl_xor(acc0, m, 64); acc1 += __shfl_xor(acc1, m, 64);
        acc2 += __shfl_xor(acc2, m, 64); acc3 += __shfl_xor(acc3, m, 64);
        acc4 += __shfl_xor(acc4, m, 64); acc5 += __shfl_xor(acc5, m, 64);
        acc6 += __shfl_xor(acc6, m, 64); acc7 += __shfl_xor(acc7, m, 64);
        sm   += __shfl_xor(sm, m, 64);
    }
    if (lane < 8) {
        float inv = 1.f / sm;
        float4 bl = *(const float4*)&b1[lane * 8];
        float4 bh = *(const float4*)&b1[lane * 8 + 4];
        float4 lo, hi;
        lo.x = acc0 * inv + bl.x; lo.x = lo.x > 0.f ? lo.x : expm1f(lo.x);
        lo.y = acc1 * inv + bl.y; lo.y = lo.y > 0.f ? lo.y : expm1f(lo.y);
        lo.z = acc2 * inv + bl.z; lo.z = lo.z > 0.f ? lo.z : expm1f(lo.z);
        lo.w = acc3 * inv + bl.w; lo.w = lo.w > 0.f ? lo.w : expm1f(lo.w);
        hi.x = acc4 * inv + bh.x; hi.x = hi.x > 0.f ? hi.x : expm1f(hi.x);
        hi.y = acc5 * inv + bh.y; hi.y = hi.y > 0.f ? hi.y : expm1f(hi.y);
        hi.z = acc6 * inv + bh.z; hi.z = hi.z > 0.f ? hi.z : expm1f(hi.z);
        hi.w = acc7 * inv + bh.w; hi.w = hi.w > 0.f ? hi.w : expm1f(hi.w);
        *(float4*)&xh[(size_t)d * 64 + lane * 8]     = lo;
        *(float4*)&xh[(size_t)d * 64 + lane * 8 + 4] = hi;
    }
}

// ============ gemm2: h2 = xh @ W2 (bf16 out), logits a_s2 + packed (a_d2, e_self2) ============
__global__ __launch_bounds__(256) void gemm2(const float* __restrict__ xh,
                                             const float* __restrict__ W2S,
                                             const float* __restrict__ att_s,
                                             const float* __restrict__ att_d,
                                             unsigned short* __restrict__ h2b,
                                             float* __restrict__ a_s2,
                                             float2* __restrict__ nd2) {
    int lane = threadIdx.x & 63;
    int wv   = __builtin_amdgcn_readfirstlane(threadIdx.x >> 6);
    int n0   = blockIdx.x * 16 + wv * 4;
    const float* __restrict__ xr = xh + (size_t)n0 * 64;            // uniform -> s_load
    const float4* __restrict__ wp = (const float4*)W2S;
    float4 acc = {0.f, 0.f, 0.f, 0.f};
#pragma unroll 4
    for (int k4 = 0; k4 < 16; ++k4) {
        float4 w = wp[k4 * 64 + lane];
        const float* xk = xr + k4 * 4;
        acc.x += xk[0]   * w.x + xk[1]   * w.y + xk[2]   * w.z + xk[3]   * w.w;
        acc.y += xk[64]  * w.x + xk[65]  * w.y + xk[66]  * w.z + xk[67]  * w.w;
        acc.z += xk[128] * w.x + xk[129] * w.y + xk[130] * w.z + xk[131] * w.w;
        acc.w += xk[192] * w.x + xk[193] * w.y + xk[194] * w.z + xk[195] * w.w;
    }
    float as_l = att_s[lane], ad_l = att_d[lane];
    float av[4] = {acc.x, acc.y, acc.z, acc.w};
#pragma unroll
    for (int r = 0; r < 4; ++r) {
        float a = av[r];
        h2b[(size_t)(n0 + r) * 64 + lane] = f2bf(a);
        float ps = a * as_l, pd = a * ad_l;
#pragma unroll
        for (int m = 1; m < 64; m <<= 1) { ps += __shfl_xor(ps, m, 64); pd += __shfl_xor(pd, m, 64); }
        if (lane == 0) {
            a_s2[n0 + r] = ps;
            nd2[n0 + r]  = make_float2(pd, lrelu(ps + pd));
        }
    }
}

// ============ eexp2: one thread per edge (1 head) ============
__global__ __launch_bounds__(256) void eexp2(const int* __restrict__ srclist,
                                             const int* __restrict__ dlist,
                                             const float* __restrict__ a_s2,
                                             const float2* __restrict__ nd2,
                                             unsigned short* __restrict__ exb2) {
    int e = blockIdx.x * 256 + threadIdx.x;             // grid exact: NE
    int s = srclist[e], d = dlist[e];
    float2 nd = nd2[d];
    exb2[e] = f2bf(__expf(lrelu(a_s2[s] + nd.x) - nd.y));
}

// ============ agg2: wave/node, 8 lanes/edge; writes out = agg + b2 ============
__global__ __launch_bounds__(256) void agg2(const int* __restrict__ srclist,
                                            const int* __restrict__ offs,
                                            const int* __restrict__ degv,
                                            const unsigned short* __restrict__ exb2,
                                            const unsigned short* __restrict__ h2b,
                                            const float* __restrict__ b2,
                                            float* __restrict__ out) {
    int wv   = threadIdx.x >> 6;
    int lane = threadIdx.x & 63;
    int d    = blockIdx.x * 4 + wv;
    int base = offs[d], dg = degv[d];
    int sub  = lane >> 3, hch = lane & 7;
    float acc0 = 0.f, acc1 = 0.f, acc2 = 0.f, acc3 = 0.f;
    float acc4 = 0.f, acc5 = 0.f, acc6 = 0.f, acc7 = 0.f;
    float sm = 0.f;
#pragma unroll 2
    for (int k = sub; k < dg; k += 8) {
        int s = srclist[base + k];
        float ex = bf2f(exb2[base + k]);
        uint4 hv = *(const uint4*)&h2b[(size_t)s * 64 + hch * 8];
        acc0 += __uint_as_float(hv.x << 16)          * ex;
        acc1 += __uint_as_float(hv.x & 0xffff0000u)  * ex;
        acc2 += __uint_as_float(hv.y << 16)          * ex;
        acc3 += __uint_as_float(hv.y & 0xffff0000u)  * ex;
        acc4 += __uint_as_float(hv.z << 16)          * ex;
        acc5 += __uint_as_float(hv.z & 0xffff0000u)  * ex;
        acc6 += __uint_as_float(hv.w << 16)          * ex;
        acc7 += __uint_as_float(hv.w & 0xffff0000u)  * ex;
        sm += ex;
    }
    if (sub == 0) {
        uint4 hv = *(const uint4*)&h2b[(size_t)d * 64 + hch * 8];
        acc0 += __uint_as_float(hv.x << 16);
        acc1 += __uint_as_float(hv.x & 0xffff0000u);
        acc2 += __uint_as_float(hv.y << 16);
        acc3 += __uint_as_float(hv.y & 0xffff0000u);
        acc4 += __uint_as_float(hv.z << 16);
        acc5 += __uint_as_float(hv.z & 0xffff0000u);
        acc6 += __uint_as_float(hv.w << 16);
        acc7 += __uint_as_float(hv.w & 0xffff0000u);
        sm += 1.f;
    }
#pragma unroll
    for (int m = 8; m < 64; m <<= 1) {
        acc0 += __shfl_xor(acc0, m, 64); acc1 += __shfl_xor(acc1, m, 64);
        acc2 += __shfl_xor(acc2, m, 64); acc3 += __shfl_xor(acc3, m, 64);
        acc4 += __shfl_xor(acc4, m, 64); acc5 += __shfl_xor(acc5, m, 64);
        acc6 += __shfl_xor(acc6, m, 64); acc7 += __shfl_xor(acc7, m, 64);
        sm   += __shfl_xor(sm, m, 64);
    }
    if (lane < 8) {
        float inv = 1.f / sm;
        float4 bl = *(const float4*)&b2[lane * 8];
        float4 bh = *(const float4*)&b2[lane * 8 + 4];
        float4 lo, hi;
        lo.x = acc0 * inv + bl.x; lo.y = acc1 * inv + bl.y;
        lo.z = acc2 * inv + bl.z; lo.w = acc3 * inv + bl.w;
        hi.x = acc4 * inv + bh.x; hi.y = acc5 * inv + bh.y;
        hi.z = acc6 * inv + bh.z; hi.w = acc7 * inv + bh.w;
        *(float4*)&out[(size_t)d * 64 + lane * 8]     = lo;
        *(float4*)&out[(size_t)d * 64 + lane * 8 + 4] = hi;
    }
}

extern "C" void kernel_launch(void* const* d_in, const int* in_sizes, int n_in,
                              void* d_out, int out_size, void* d_ws, size_t ws_size,
                              hipStream_t stream) {
    const float* x   = (const float*)d_in[0];
    const int*   ei  = (const int*)d_in[1];
    const float* W1  = (const float*)d_in[2];
    const float* as1 = (const float*)d_in[3];
    const float* ad1 = (const float*)d_in[4];
    const float* b1  = (const float*)d_in[5];
    const float* W2  = (const float*)d_in[6];
    const float* as2 = (const float*)d_in[7];
    const float* ad2 = (const float*)d_in[8];
    const float* b2  = (const float*)d_in[9];
    float* out = (float*)d_out;

    float* ws = (float*)d_ws;
    // [0, 1.6M)   h1b (3.2M ushort); exb2 aliases (dead after agg1 reads h1b)
    unsigned short* h1b  = (unsigned short*)ws;
    unsigned short* exb2 = (unsigned short*)ws;
    // [1.6M, 4.8M) exb1 (6.4M ushort); h2b aliases front half (written after exb1 dead)
    unsigned short* exb1 = (unsigned short*)(ws + 1600000);
    unsigned short* h2b  = (unsigned short*)(ws + 1600000);
    float*  xh   = ws + 4800000;             // 3.2M floats
    float*  a_s1 = ws + 8000000;             // 400k
    float2* nd1  = (float2*)(ws + 8400000);  // 400k float2
    float*  a_s2 = ws + 9200000;             // 50k
    float2* nd2  = (float2*)(ws + 9250000);  // 50k float2
    int* deg     = (int*)(ws + 9350000);     // 50k
    int* offs    = deg + 50000;
    int* cursor  = offs + 50000;
    int* bsum    = cursor + 50000;           // 256
    int* srclist = bsum + 256;               // 800k
    int* dlist   = srclist + 800000;         // 800k
    float* W1S   = (float*)(dlist + 800000); // 8192
    float* W2S   = W1S + 8192;               // 4096

    // ---- CSR build + weight swizzle
    hipMemsetAsync(deg, 0, (size_t)NN * 4, stream);
    hist<<<3125, 256, 0, stream>>>(ei, deg);
    prep<<<48, 256, 0, stream>>>(W1, W2, W1S, W2S);
    scan1<<<256, 256, 0, stream>>>(deg, offs, bsum);
    scan2<<<1, 256, 0, stream>>>(bsum);
    scan3<<<196, 256, 0, stream>>>(offs, bsum, cursor);
    scatter<<<3125, 256, 0, stream>>>(ei, cursor, srclist, dlist);

    // ---- layer 1
    gemm1<<<3125, 256, 0, stream>>>(x, W1S, as1, ad1, h1b, a_s1, nd1);
    eexp1<<<25000, 256, 0, stream>>>(srclist, dlist, a_s1, nd1, exb1);
    agg1<<<12500, 256, 0, stream>>>(srclist, offs, deg, exb1, h1b, b1, xh);

    // ---- layer 2
    gemm2<<<3125, 256, 0, stream>>>(xh, W2S, as2, ad2, h2b, a_s2, nd2);
    eexp2<<<3125, 256, 0, stream>>>(srclist, dlist, a_s2, nd2, exb2);
    agg2<<<12500, 256, 0, stream>>>(srclist, offs, deg, exb2, h2b, b2, out);
}

// Round 8
// 168.841 us; speedup vs baseline: 1.3082x; 1.3082x over previous
//
#include <hip/hip_runtime.h>

#define NN 50000
#define NE 800000
#define NEG_SLOPE 0.2f

__device__ __forceinline__ float lrelu(float v) { return v > 0.f ? v : NEG_SLOPE * v; }
__device__ __forceinline__ float bf2f(unsigned short u) { return __uint_as_float((unsigned)u << 16); }
__device__ __forceinline__ unsigned short f2bf(float f) {
    unsigned u = __float_as_uint(f);
    return (unsigned short)((u + 0x7FFFu + ((u >> 16) & 1u)) >> 16);   // RNE
}

// ============ CSR build (dst-sorted), atomic only in hist ============
__global__ void hist(const int* __restrict__ ei, int* __restrict__ deg,
                     int* __restrict__ rank) {
    int e = blockIdx.x * blockDim.x + threadIdx.x;
    if (e < NE) rank[e] = atomicAdd(&deg[ei[NE + e]], 1);
}

__global__ __launch_bounds__(256) void scan1(const int* __restrict__ deg,
                                             int* __restrict__ offs, int* __restrict__ bsum) {
    __shared__ int tmp[256];
    int i = blockIdx.x * 256 + threadIdx.x;
    int v = (i < NN) ? deg[i] : 0;
    tmp[threadIdx.x] = v;
    __syncthreads();
    for (int o = 1; o < 256; o <<= 1) {
        int t = (threadIdx.x >= o) ? tmp[threadIdx.x - o] : 0;
        __syncthreads();
        tmp[threadIdx.x] += t;
        __syncthreads();
    }
    if (i < NN) offs[i] = tmp[threadIdx.x] - v;          // exclusive, block-local
    if (threadIdx.x == 255) bsum[blockIdx.x] = tmp[255];
}

__global__ __launch_bounds__(256) void scan2(int* __restrict__ bsum) {
    __shared__ int tmp[256];
    int v = bsum[threadIdx.x];
    tmp[threadIdx.x] = v;
    __syncthreads();
    for (int o = 1; o < 256; o <<= 1) {
        int t = (threadIdx.x >= o) ? tmp[threadIdx.x - o] : 0;
        __syncthreads();
        tmp[threadIdx.x] += t;
        __syncthreads();
    }
    bsum[threadIdx.x] = tmp[threadIdx.x] - v;
}

// finalize: offs becomes GLOBAL exclusive prefix (single source of truth for all consumers)
__global__ void scan3(int* __restrict__ offs, const int* __restrict__ bsum) {
    int i = blockIdx.x * blockDim.x + threadIdx.x;
    if (i < NN) offs[i] += bsum[i >> 8];
}

// atomic-free scatter: pos = global offs + per-edge rank
__global__ void scatter(const int* __restrict__ ei, const int* __restrict__ rank,
                        const int* __restrict__ offs, int* __restrict__ srclist) {
    int e = blockIdx.x * blockDim.x + threadIdx.x;
    if (e < NE) {
        int d = ei[NE + e];
        srclist[offs[d] + rank[e]] = ei[e];
    }
}

// ============ weight swizzle: W[k,c] -> WS[(k4*64+c)*4+j], k=4*k4+j ============
__global__ void prep(const float* __restrict__ W1, const float* __restrict__ W2,
                     float* __restrict__ W1S, float* __restrict__ W2S) {
    int tid = blockIdx.x * blockDim.x + threadIdx.x;
    if (tid < 8192) {
        int k = tid >> 6, c = tid & 63;
        W1S[((k >> 2) * 64 + c) * 4 + (k & 3)] = W1[k * 64 + c];
    } else if (tid < 12288) {
        int t = tid - 8192;
        int k = t >> 6, c = t & 63;
        W2S[((k >> 2) * 64 + c) * 4 + (k & 3)] = W2[k * 64 + c];
    }
}

// ============ gemm1: h1 = x @ W1 (bf16 out), logits a_s1 + packed (a_d, e_self) ============
__global__ __launch_bounds__(256) void gemm1(const float* __restrict__ x,
                                             const float* __restrict__ W1S,
                                             const float* __restrict__ att_s,
                                             const float* __restrict__ att_d,
                                             unsigned short* __restrict__ h1b,
                                             float* __restrict__ a_s,
                                             float2* __restrict__ nd1) {
    int lane = threadIdx.x & 63;
    int wv   = __builtin_amdgcn_readfirstlane(threadIdx.x >> 6);
    int n0   = blockIdx.x * 16 + wv * 4;
    const float* __restrict__ xr = x + (size_t)n0 * 128;            // uniform ptr -> s_load
    const float4* __restrict__ wp = (const float4*)W1S;
    float4 acc = {0.f, 0.f, 0.f, 0.f};
#pragma unroll 4
    for (int k4 = 0; k4 < 32; ++k4) {
        float4 w = wp[k4 * 64 + lane];
        const float* xk = xr + k4 * 4;
        acc.x += xk[0]   * w.x + xk[1]   * w.y + xk[2]   * w.z + xk[3]   * w.w;
        acc.y += xk[128] * w.x + xk[129] * w.y + xk[130] * w.z + xk[131] * w.w;
        acc.z += xk[256] * w.x + xk[257] * w.y + xk[258] * w.z + xk[259] * w.w;
        acc.w += xk[384] * w.x + xk[385] * w.y + xk[386] * w.z + xk[387] * w.w;
    }
    float as_l = att_s[lane], ad_l = att_d[lane];
    float av[4] = {acc.x, acc.y, acc.z, acc.w};
#pragma unroll
    for (int r = 0; r < 4; ++r) {
        float a = av[r];
        h1b[(size_t)(n0 + r) * 64 + lane] = f2bf(a);
        float ps = a * as_l, pd = a * ad_l;
        ps += __shfl_xor(ps, 1, 64); pd += __shfl_xor(pd, 1, 64);
        ps += __shfl_xor(ps, 2, 64); pd += __shfl_xor(pd, 2, 64);
        ps += __shfl_xor(ps, 4, 64); pd += __shfl_xor(pd, 4, 64);
        if ((lane & 7) == 0) {
            int h = lane >> 3;
            a_s[(n0 + r) * 8 + h] = ps;
            nd1[(n0 + r) * 8 + h] = make_float2(pd, lrelu(ps + pd));
        }
    }
}

// ============ agg1: wave/node, 8 lanes/edge, exp in-loop; writes xh = elu(agg+b1) ============
__global__ __launch_bounds__(256) void agg1(const int* __restrict__ srclist,
                                            const int* __restrict__ offs,
                                            const int* __restrict__ degv,
                                            const float* __restrict__ a_s,
                                            const float2* __restrict__ nd1,
                                            const unsigned short* __restrict__ h1b,
                                            const float* __restrict__ b1,
                                            float* __restrict__ xh) {
    int wv   = threadIdx.x >> 6;
    int lane = threadIdx.x & 63;
    int d    = blockIdx.x * 4 + wv;
    int base = offs[d], dg = degv[d];
    int sub  = lane >> 3, hch = lane & 7;              // 8-lane group per edge; lane = head
    float2 nd = nd1[d * 8 + hch];                      // (a_d, e_self) for this head
    float acc0 = 0.f, acc1 = 0.f, acc2 = 0.f, acc3 = 0.f;
    float acc4 = 0.f, acc5 = 0.f, acc6 = 0.f, acc7 = 0.f;
    float sm = 0.f;
#pragma unroll 2
    for (int k = sub; k < dg; k += 8) {
        int s = srclist[base + k];
        float ex = __expf(lrelu(a_s[s * 8 + hch] + nd.x) - nd.y);
        uint4 hv = *(const uint4*)&h1b[(size_t)s * 64 + hch * 8];
        acc0 += __uint_as_float(hv.x << 16)          * ex;
        acc1 += __uint_as_float(hv.x & 0xffff0000u)  * ex;
        acc2 += __uint_as_float(hv.y << 16)          * ex;
        acc3 += __uint_as_float(hv.y & 0xffff0000u)  * ex;
        acc4 += __uint_as_float(hv.z << 16)          * ex;
        acc5 += __uint_as_float(hv.z & 0xffff0000u)  * ex;
        acc6 += __uint_as_float(hv.w << 16)          * ex;
        acc7 += __uint_as_float(hv.w & 0xffff0000u)  * ex;
        sm += ex;
    }
    if (sub == 0) {                                    // self loop: exp(es - es) = 1
        uint4 hv = *(const uint4*)&h1b[(size_t)d * 64 + hch * 8];
        acc0 += __uint_as_float(hv.x << 16);
        acc1 += __uint_as_float(hv.x & 0xffff0000u);
        acc2 += __uint_as_float(hv.y << 16);
        acc3 += __uint_as_float(hv.y & 0xffff0000u);
        acc4 += __uint_as_float(hv.z << 16);
        acc5 += __uint_as_float(hv.z & 0xffff0000u);
        acc6 += __uint_as_float(hv.w << 16);
        acc7 += __uint_as_float(hv.w & 0xffff0000u);
        sm += 1.f;
    }
#pragma unroll
    for (int m = 8; m < 64; m <<= 1) {
        acc0 += __shfl_xor(acc0, m, 64); acc1 += __shfl_xor(acc1, m, 64);
        acc2 += __shfl_xor(acc2, m, 64); acc3 += __shfl_xor(acc3, m, 64);
        acc4 += __shfl_xor(acc4, m, 64); acc5 += __shfl_xor(acc5, m, 64);
        acc6 += __shfl_xor(acc6, m, 64); acc7 += __shfl_xor(acc7, m, 64);
        sm   += __shfl_xor(sm, m, 64);
    }
    if (lane < 8) {
        float inv = 1.f / sm;
        float4 bl = *(const float4*)&b1[lane * 8];
        float4 bh = *(const float4*)&b1[lane * 8 + 4];
        float4 lo, hi;
        lo.x = acc0 * inv + bl.x; lo.x = lo.x > 0.f ? lo.x : expm1f(lo.x);
        lo.y = acc1 * inv + bl.y; lo.y = lo.y > 0.f ? lo.y : expm1f(lo.y);
        lo.z = acc2 * inv + bl.z; lo.z = lo.z > 0.f ? lo.z : expm1f(lo.z);
        lo.w = acc3 * inv + bl.w; lo.w = lo.w > 0.f ? lo.w : expm1f(lo.w);
        hi.x = acc4 * inv + bh.x; hi.x = hi.x > 0.f ? hi.x : expm1f(hi.x);
        hi.y = acc5 * inv + bh.y; hi.y = hi.y > 0.f ? hi.y : expm1f(hi.y);
        hi.z = acc6 * inv + bh.z; hi.z = hi.z > 0.f ? hi.z : expm1f(hi.z);
        hi.w = acc7 * inv + bh.w; hi.w = hi.w > 0.f ? hi.w : expm1f(hi.w);
        *(float4*)&xh[(size_t)d * 64 + lane * 8]     = lo;
        *(float4*)&xh[(size_t)d * 64 + lane * 8 + 4] = hi;
    }
}

// ============ gemm2: h2 = xh @ W2 (bf16 out), logits a_s2 + packed (a_d2, e_self2) ============
__global__ __launch_bounds__(256) void gemm2(const float* __restrict__ xh,
                                             const float* __restrict__ W2S,
                                             const float* __restrict__ att_s,
                                             const float* __restrict__ att_d,
                                             unsigned short* __restrict__ h2b,
                                             float* __restrict__ a_s2,
                                             float2* __restrict__ nd2) {
    int lane = threadIdx.x & 63;
    int wv   = __builtin_amdgcn_readfirstlane(threadIdx.x >> 6);
    int n0   = blockIdx.x * 16 + wv * 4;
    const float* __restrict__ xr = xh + (size_t)n0 * 64;            // uniform -> s_load
    const float4* __restrict__ wp = (const float4*)W2S;
    float4 acc = {0.f, 0.f, 0.f, 0.f};
#pragma unroll 4
    for (int k4 = 0; k4 < 16; ++k4) {
        float4 w = wp[k4 * 64 + lane];
        const float* xk = xr + k4 * 4;
        acc.x += xk[0]   * w.x + xk[1]   * w.y + xk[2]   * w.z + xk[3]   * w.w;
        acc.y += xk[64]  * w.x + xk[65]  * w.y + xk[66]  * w.z + xk[67]  * w.w;
        acc.z += xk[128] * w.x + xk[129] * w.y + xk[130] * w.z + xk[131] * w.w;
        acc.w += xk[192] * w.x + xk[193] * w.y + xk[194] * w.z + xk[195] * w.w;
    }
    float as_l = att_s[lane], ad_l = att_d[lane];
    float av[4] = {acc.x, acc.y, acc.z, acc.w};
#pragma unroll
    for (int r = 0; r < 4; ++r) {
        float a = av[r];
        h2b[(size_t)(n0 + r) * 64 + lane] = f2bf(a);
        float ps = a * as_l, pd = a * ad_l;
#pragma unroll
        for (int m = 1; m < 64; m <<= 1) { ps += __shfl_xor(ps, m, 64); pd += __shfl_xor(pd, m, 64); }
        if (lane == 0) {
            a_s2[n0 + r] = ps;
            nd2[n0 + r]  = make_float2(pd, lrelu(ps + pd));
        }
    }
}

// ============ agg2: wave/node, 8 lanes/edge, exp in-loop; writes out = agg + b2 ============
__global__ __launch_bounds__(256) void agg2(const int* __restrict__ srclist,
                                            const int* __restrict__ offs,
                                            const int* __restrict__ degv,
                                            const float* __restrict__ a_s2,
                                            const float2* __restrict__ nd2,
                                            const unsigned short* __restrict__ h2b,
                                            const float* __restrict__ b2,
                                            float* __restrict__ out) {
    int wv   = threadIdx.x >> 6;
    int lane = threadIdx.x & 63;
    int d    = blockIdx.x * 4 + wv;
    int base = offs[d], dg = degv[d];
    int sub  = lane >> 3, hch = lane & 7;
    float2 nd = nd2[d];
    float acc0 = 0.f, acc1 = 0.f, acc2 = 0.f, acc3 = 0.f;
    float acc4 = 0.f, acc5 = 0.f, acc6 = 0.f, acc7 = 0.f;
    float sm = 0.f;
#pragma unroll 2
    for (int k = sub; k < dg; k += 8) {
        int s = srclist[base + k];
        float ex = __expf(lrelu(a_s2[s] + nd.x) - nd.y);   // same in all 8 lanes of group
        uint4 hv = *(const uint4*)&h2b[(size_t)s * 64 + hch * 8];
        acc0 += __uint_as_float(hv.x << 16)          * ex;
        acc1 += __uint_as_float(hv.x & 0xffff0000u)  * ex;
        acc2 += __uint_as_float(hv.y << 16)          * ex;
        acc3 += __uint_as_float(hv.y & 0xffff0000u)  * ex;
        acc4 += __uint_as_float(hv.z << 16)          * ex;
        acc5 += __uint_as_float(hv.z & 0xffff0000u)  * ex;
        acc6 += __uint_as_float(hv.w << 16)          * ex;
        acc7 += __uint_as_float(hv.w & 0xffff0000u)  * ex;
        sm += ex;
    }
    if (sub == 0) {
        uint4 hv = *(const uint4*)&h2b[(size_t)d * 64 + hch * 8];
        acc0 += __uint_as_float(hv.x << 16);
        acc1 += __uint_as_float(hv.x & 0xffff0000u);
        acc2 += __uint_as_float(hv.y << 16);
        acc3 += __uint_as_float(hv.y & 0xffff0000u);
        acc4 += __uint_as_float(hv.z << 16);
        acc5 += __uint_as_float(hv.z & 0xffff0000u);
        acc6 += __uint_as_float(hv.w << 16);
        acc7 += __uint_as_float(hv.w & 0xffff0000u);
        sm += 1.f;
    }
#pragma unroll
    for (int m = 8; m < 64; m <<= 1) {
        acc0 += __shfl_xor(acc0, m, 64); acc1 += __shfl_xor(acc1, m, 64);
        acc2 += __shfl_xor(acc2, m, 64); acc3 += __shfl_xor(acc3, m, 64);
        acc4 += __shfl_xor(acc4, m, 64); acc5 += __shfl_xor(acc5, m, 64);
        acc6 += __shfl_xor(acc6, m, 64); acc7 += __shfl_xor(acc7, m, 64);
        sm   += __shfl_xor(sm, m, 64);
    }
    if (lane < 8) {
        float inv = 1.f / sm;
        float4 bl = *(const float4*)&b2[lane * 8];
        float4 bh = *(const float4*)&b2[lane * 8 + 4];
        float4 lo, hi;
        lo.x = acc0 * inv + bl.x; lo.y = acc1 * inv + bl.y;
        lo.z = acc2 * inv + bl.z; lo.w = acc3 * inv + bl.w;
        hi.x = acc4 * inv + bh.x; hi.y = acc5 * inv + bh.y;
        hi.z = acc6 * inv + bh.z; hi.w = acc7 * inv + bh.w;
        *(float4*)&out[(size_t)d * 64 + lane * 8]     = lo;
        *(float4*)&out[(size_t)d * 64 + lane * 8 + 4] = hi;
    }
}

extern "C" void kernel_launch(void* const* d_in, const int* in_sizes, int n_in,
                              void* d_out, int out_size, void* d_ws, size_t ws_size,
                              hipStream_t stream) {
    const float* x   = (const float*)d_in[0];
    const int*   ei  = (const int*)d_in[1];
    const float* W1  = (const float*)d_in[2];
    const float* as1 = (const float*)d_in[3];
    const float* ad1 = (const float*)d_in[4];
    const float* b1  = (const float*)d_in[5];
    const float* W2  = (const float*)d_in[6];
    const float* as2 = (const float*)d_in[7];
    const float* ad2 = (const float*)d_in[8];
    const float* b2  = (const float*)d_in[9];
    float* out = (float*)d_out;

    float* ws = (float*)d_ws;
    unsigned short* h1b = (unsigned short*)ws;             // 3.2M ushort  [0,1.6M)
    unsigned short* h2b = (unsigned short*)(ws + 1600000); // 3.2M ushort  [1.6M,3.2M)
    float*  xh   = ws + 3200000;             // 3.2M floats
    float*  a_s1 = ws + 6400000;             // 400k
    float2* nd1  = (float2*)(ws + 6800000);  // 400k float2 (800k floats)
    float*  a_s2 = ws + 7600000;             // 50k
    float2* nd2  = (float2*)(ws + 7650000);  // 50k float2 (100k floats)
    int* deg     = (int*)(ws + 7750000);     // 50k
    int* offs    = deg + 50000;              // 50k
    int* bsum    = offs + 50000;             // 256
    int* rank    = bsum + 256;               // 800k
    int* srclist = rank + 800000;            // 800k
    float* W1S   = (float*)(srclist + 800000); // 8192
    float* W2S   = W1S + 8192;               // 4096

    // ---- CSR build (atomic only in hist) + weight swizzle
    hipMemsetAsync(deg, 0, (size_t)NN * 4, stream);
    hist<<<3125, 256, 0, stream>>>(ei, deg, rank);
    prep<<<48, 256, 0, stream>>>(W1, W2, W1S, W2S);
    scan1<<<256, 256, 0, stream>>>(deg, offs, bsum);
    scan2<<<1, 256, 0, stream>>>(bsum);
    scan3<<<196, 256, 0, stream>>>(offs, bsum);         // offs -> GLOBAL prefix
    scatter<<<3125, 256, 0, stream>>>(ei, rank, offs, srclist);

    // ---- layer 1
    gemm1<<<3125, 256, 0, stream>>>(x, W1S, as1, ad1, h1b, a_s1, nd1);
    agg1<<<12500, 256, 0, stream>>>(srclist, offs, deg, a_s1, nd1, h1b, b1, xh);

    // ---- layer 2
    gemm2<<<3125, 256, 0, stream>>>(xh, W2S, as2, ad2, h2b, a_s2, nd2);
    agg2<<<12500, 256, 0, stream>>>(srclist, offs, deg, a_s2, nd2, h2b, b2, out);
}